// Round 14
// baseline (250.823 us; speedup 1.0000x reference)
//
#include <hip/hip_runtime.h>
#include <hip/hip_bf16.h>

typedef __attribute__((ext_vector_type(8))) short short8;
typedef __attribute__((ext_vector_type(4))) float f32x4;
typedef __attribute__((ext_vector_type(4))) float float4v;
typedef __attribute__((ext_vector_type(8))) unsigned short ushort8;

// RNE float -> bf16 payload
__device__ __forceinline__ unsigned short f2bf(float f) {
    union { float f; unsigned u; } x; x.f = f;
    unsigned r = x.u + 0x7FFFu + ((x.u >> 16) & 1u);
    return (unsigned short)(r >> 16);
}

// C[k][n] = s(k) * cos(pi * k * (2n+1) / (2N)), N = 512, ortho norm.
__global__ __launch_bounds__(256) void make_dct_mat(unsigned short* __restrict__ Cm) {
    int idx = blockIdx.x * 256 + threadIdx.x;
    int k = idx >> 9;
    int n = idx & 511;
    int m = (k * (2 * n + 1)) & 2047;             // mod 4N
    float ang = (3.14159265358979323846f / 1024.0f) * (float)m;
    float s = (k == 0) ? 0.04419417382415922f : 0.0625f;
    Cm[idx] = f2bf(s * cosf(ang));
}

#define GLD16(g, l) __builtin_amdgcn_global_load_lds( \
    (const __attribute__((address_space(1))) void*)(g), \
    (__attribute__((address_space(3))) void*)(l), 16, 0, 0)
#define BAR()    asm volatile("s_barrier" ::: "memory")
#define VMCNT(n) asm volatile("s_waitcnt vmcnt(" #n ")" ::: "memory")
#define LGKM0()  asm volatile("s_waitcnt lgkmcnt(0)" ::: "memory")
#define MEMORD() asm volatile("" ::: "memory")   // pin VMEM issue order (FIFO ledger)

// D[img] = A * B[img]^T, A = DCT matrix (L2-hot), per-image 512x512.
// 8-phase template port: BM=BN=256, BK=64, 8 waves (2Mx4N), wave tile 128x64.
// 8 K-tiles x 4 phases; per phase: {ds_read quadrant frags; stage/issue;
// counted vmcnt (4, never 0 mid-loop); s_barrier; lgkmcnt(0); MFMA; s_barrier}.
// s1 (fp32 B): quarter-chunk reg staging (2 float4 = 8 VGPR per chunk, two
// alternating buffers cU/cV, load at phase p -> cvt+ds_write at phase p+1)
// -> ledger peak 16 VGPR (was 32) to kill the R12 spill.
// Sub-tile LDS layout = proven zero-conflict XOR (slotL = slotG ^ ((row>>1)&3)).
template <bool B_IS_F32, bool OUT_F32>
__device__ __forceinline__ void dct_gemm_body(
    const unsigned short* __restrict__ A,
    const void* __restrict__ Ball,
    void* __restrict__ Dall)
{
    // [dbuf][half][ksub][128 rows x 32 K] bf16 = 8 KB subtiles; 64 KB each op.
    __shared__ unsigned short As[2][2][2][4096];
    __shared__ unsigned short Bs[2][2][2][4096];

    // XCD-bijective swizzle (1024 % 8 == 0); an image's 4 tiles stay adjacent
    // on one XCD so the twin R-block's B-panel re-read is an L2 hit.
    int wg  = blockIdx.x;
    int cpx = gridDim.x >> 3;
    int swz = (wg & 7) * cpx + (wg >> 3);
    int img = swz >> 2;
    int R0  = ((swz >> 1) & 1) * 256;   // C-row tile (output rows)
    int C0  = (swz & 1) * 256;          // B-row tile (output cols)

    int t    = threadIdx.x;             // 0..511
    int lane = t & 63;
    int wid  = t >> 6;                  // 0..7
    int wm   = wid >> 2;                // 0..1 -> rows [wm*128,+128)
    int wn   = wid & 3;                 // 0..3 -> cols [wn*64,+64)
    int l15  = lane & 15;
    const int roff = ((lane >> 4) ^ ((lane >> 1) & 3)) * 8;   // proven read swizzle

    const size_t imgoff = (size_t)img * (512 * 512);

    // ---- staging addresses (pre-swizzled 16B slot) ----
    const int sXor = ((t & 3) ^ ((t >> 3) & 3)) * 8;
    const unsigned short* gA = A
        + (size_t)(R0 + (t >> 8) * 128 + ((t >> 2) & 63)) * 512 + sXor;
    const int bRow = C0 + ((t >> 7) & 3) * 64 + ((t >> 2) & 31);
    const unsigned short* gB16 = nullptr;
    const float* gBf = nullptr;
    if constexpr (B_IS_F32)
        gBf = (const float*)Ball + imgoff + (size_t)bRow * 512 + sXor;
    else
        gB16 = (const unsigned short*)Ball + imgoff + (size_t)bRow * 512 + sXor;

    auto stageA = [&](int d, int kt, int h) {   // 2 GLD16
        GLD16(gA + (size_t)h * 64 * 512 + kt * 64,      &As[d][h][0][t * 8]);
        GLD16(gA + (size_t)h * 64 * 512 + kt * 64 + 32, &As[d][h][1][t * 8]);
    };
    auto stageB = [&](int d, int kt, int h) {   // 2 GLD16 (s2)
        GLD16(gB16 + (size_t)h * 32 * 512 + kt * 64,      &Bs[d][h][0][t * 8]);
        GLD16(gB16 + (size_t)h * 32 * 512 + kt * 64 + 32, &Bs[d][h][1][t * 8]);
    };

    // s1 quarter-chunk staging: chunk (h,ks) = 2 float4 / thread.
    float4v cU[2], cV[2];
    auto loadChunk = [&](float4v* cb, int kt, int h, int ks) {   // 2 vmem loads
        const float* p = gBf + (size_t)h * 32 * 512 + kt * 64 + ks * 32;
        cb[0] = *(const float4v*)(p);
        cb[1] = *(const float4v*)(p + 4);
    };
    auto writeChunk = [&](int dbuf, int h, int ks, const float4v* cb) { // 1 ds_write_b128
        union { ushort8 u8; __hip_bfloat162 h2[4]; } u;
        u.h2[0] = __float22bfloat162_rn(float2{cb[0].x, cb[0].y});
        u.h2[1] = __float22bfloat162_rn(float2{cb[0].z, cb[0].w});
        u.h2[2] = __float22bfloat162_rn(float2{cb[1].x, cb[1].y});
        u.h2[3] = __float22bfloat162_rn(float2{cb[1].z, cb[1].w});
        *(ushort8*)(&Bs[dbuf][h][ks][t * 8]) = u.u8;
    };

    short8 avA[4][2], avB[4][2], bvA[2][2], bvB[2][2];
    auto readA = [&](short8 av[4][2], int d, int mh) {    // 8 ds_read_b128
        #pragma unroll
        for (int mq = 0; mq < 4; ++mq)
            #pragma unroll
            for (int ks = 0; ks < 2; ++ks)
                av[mq][ks] = *(const short8*)(
                    &As[d][mh][ks][(wm * 64 + mq * 16 + l15) * 32 + roff]);
    };
    auto readB = [&](short8 bv[2][2], int d, int nh) {    // 4 ds_read_b128
        #pragma unroll
        for (int nq = 0; nq < 2; ++nq)
            #pragma unroll
            for (int ks = 0; ks < 2; ++ks)
                bv[nq][ks] = *(const short8*)(
                    &Bs[d][nh][ks][(wn * 32 + nq * 16 + l15) * 32 + roff]);
    };

    f32x4 acc[8][4] = {};
    auto mfmaQ = [&](short8 av[4][2], short8 bv[2][2], int mh, int nh) {
        __builtin_amdgcn_s_setprio(1);
        #pragma unroll
        for (int mq = 0; mq < 4; ++mq)
            #pragma unroll
            for (int nq = 0; nq < 2; ++nq)
                #pragma unroll
                for (int ks = 0; ks < 2; ++ks)
                    acc[mh*4+mq][nh*2+nq] = __builtin_amdgcn_mfma_f32_16x16x32_bf16(
                        av[mq][ks], bv[nq][ks], acc[mh*4+mq][nh*2+nq], 0, 0, 0);
        __builtin_amdgcn_s_setprio(0);
    };

    // ---- prologue: fill buf0, leaving FIFO = [Ah1(0), c3-or-B0h1] (4 ops) ----
    if constexpr (B_IS_F32) {
        loadChunk(cU, 0, 0, 0);   MEMORD();   // c0(0) [2]
        stageA(0, 0, 0);          MEMORD();   // Ah0(0) [2]
        loadChunk(cV, 0, 0, 1);               // c1(0) [2]  queue=6
        VMCNT(4);                             // retire c0
        writeChunk(0, 0, 0, cU);
        loadChunk(cU, 0, 1, 0);   MEMORD();   // c2(0) [2]
        stageA(0, 0, 1);                      // Ah1(0) [2]  queue=8
        VMCNT(4);                             // retire Ah0, c1
        writeChunk(0, 0, 1, cV);
        loadChunk(cV, 0, 1, 1);               // c3(0) [2]  queue=6
        VMCNT(4);                             // retire c2; FIFO=[Ah1,c3]
        writeChunk(0, 1, 0, cU);
        LGKM0();
        BAR();
    } else {
        stageA(0, 0, 0); MEMORD(); stageB(0, 0, 0); MEMORD();
        stageB(0, 0, 1); MEMORD(); stageA(0, 0, 1);
        VMCNT(4);               // retire A0h0,B0h0; keep [B0h1,A0h1]
        BAR();
    }

    // ---- 8 K-tiles x 4 phases; steady-state FIFO ledger in comments ----
    #pragma unroll
    for (int kt = 0; kt < 8; ++kt) {
        const int d = kt & 1, e = d ^ 1;
        // P0  entry FIFO (s1): [Ah1(kt), c3(kt)]
        readA(avA, d, 0); readB(bvA, d, 0);               // 12 ds_read
        if constexpr (B_IS_F32) {
            if (kt < 7) { loadChunk(cU, kt + 1, 0, 0); MEMORD();
                          stageA(e, kt + 1, 0);               // queue=8
                          VMCNT(4); }                         // retire Ah1(kt),c3(kt)
            else        { VMCNT(0); }
            writeChunk(d, 1, 1, cV);                          // c3(kt) -> current buf
        } else {
            if (kt < 7) { stageA(e, kt + 1, 0); VMCNT(4); }   // retire B(kt)h1
            else        { VMCNT(2); }
        }
        BAR(); LGKM0();
        mfmaQ(avA, bvA, 0, 0);
        BAR();
        // P1  FIFO (s1): [c0', Ah0']
        readB(bvB, d, 1);                                  // 4 ds_read
        if constexpr (B_IS_F32) {
            if (kt < 7) { loadChunk(cV, kt + 1, 0, 1);         // queue=6
                          VMCNT(4);                            // retire c0'
                          writeChunk(e, 0, 0, cU); }
        } else {
            if (kt < 7) { stageB(e, kt + 1, 0); VMCNT(4); }    // retire A(kt)h1
            else        { VMCNT(0); }
        }
        BAR(); LGKM0();
        mfmaQ(avA, bvB, 0, 1);
        BAR();
        // P2  FIFO (s1): [Ah0', c1']
        readA(avB, d, 1);                                  // 8 ds_read
        if constexpr (B_IS_F32) {
            if (kt < 7) { loadChunk(cU, kt + 1, 1, 0); MEMORD();
                          stageA(e, kt + 1, 1);                // queue=8
                          VMCNT(4);                            // retire Ah0',c1'
                          writeChunk(e, 0, 1, cV); }
        } else {
            if (kt < 7) { stageB(e, kt + 1, 1); VMCNT(4); }
        }
        BAR(); LGKM0();
        mfmaQ(avB, bvB, 1, 1);
        BAR();
        // P3  FIFO (s1): [c2', Ah1']
        if constexpr (B_IS_F32) {
            if (kt < 7) { loadChunk(cV, kt + 1, 1, 1);         // queue=6
                          VMCNT(4);                            // retire c2'
                          writeChunk(e, 1, 0, cU); }           // FIFO=[Ah1',c3']
        } else {
            if (kt < 7) { stageA(e, kt + 1, 1); VMCNT(4); }    // retire A'h0,B'h0
        }
        BAR(); LGKM0();
        mfmaQ(avB, bvA, 1, 0);
        BAR();
    }

    // ---- epilogue: C/D layout col = lane&15, row = (lane>>4)*4 + reg ----
    int r0 = R0 + wm * 128 + (lane >> 4) * 4;
    int c0 = C0 + wn * 64 + l15;
    if constexpr (OUT_F32) {
        float* D = (float*)Dall + imgoff;
        #pragma unroll
        for (int m = 0; m < 8; ++m)
            #pragma unroll
            for (int n = 0; n < 4; ++n)
                #pragma unroll
                for (int r = 0; r < 4; ++r)
                    D[(size_t)(r0 + (m >> 2) * 64 + (m & 3) * 16 + r) * 512
                      + c0 + (n >> 1) * 32 + (n & 1) * 16] = acc[m][n][r];
    } else {
        unsigned short* D = (unsigned short*)Dall + imgoff;
        #pragma unroll
        for (int m = 0; m < 8; ++m)
            #pragma unroll
            for (int n = 0; n < 4; ++n)
                #pragma unroll
                for (int r = 0; r < 4; ++r)
                    D[(size_t)(r0 + (m >> 2) * 64 + (m & 3) * 16 + r) * 512
                      + c0 + (n >> 1) * 32 + (n & 1) * 16] = f2bf(acc[m][n][r]);
    }
}

__global__ __launch_bounds__(512, 2) void dct_gemm_s1(
    const unsigned short* __restrict__ A, const float* __restrict__ B,
    unsigned short* __restrict__ D) {
    dct_gemm_body<true, false>(A, B, D);
}

__global__ __launch_bounds__(512, 2) void dct_gemm_s2(
    const unsigned short* __restrict__ A, const unsigned short* __restrict__ B,
    float* __restrict__ D) {
    dct_gemm_body<false, true>(A, B, D);
}

extern "C" void kernel_launch(void* const* d_in, const int* in_sizes, int n_in,
                              void* d_out, int out_size, void* d_ws, size_t ws_size,
                              hipStream_t stream) {
    const float* x = (const float*)d_in[0];
    float* out = (float*)d_out;

    // ws layout: [0, 512KB) = C matrix bf16; [1MB, 1MB+128MB) = intermediate V bf16
    unsigned short* Cm = (unsigned short*)d_ws;
    unsigned short* Tm = (unsigned short*)((char*)d_ws + (1 << 20));

    int nimg = in_sizes[0] / (512 * 512);   // 256

    make_dct_mat<<<dim3(1024), dim3(256), 0, stream>>>(Cm);
    // Stage 1: V[b] = C * X[b]^T   (B = fp32 -> quarter-chunk cvt -> bf16 LDS)
    dct_gemm_s1<<<dim3(nimg * 4), dim3(512), 0, stream>>>(Cm, x, Tm);
    // Stage 2: Y[b] = C * V[b]^T = C X C^T  (B = bf16 via global_load_lds)
    dct_gemm_s2<<<dim3(nimg * 4), dim3(512), 0, stream>>>(Cm, Tm, out);
}